// Round 8
// baseline (178.284 us; speedup 1.0000x reference)
//
#include <hip/hip_runtime.h>

typedef __attribute__((ext_vector_type(4))) _Float16 f16x4;
typedef __attribute__((ext_vector_type(4))) float f32x4;

#define NB 4096
#define TT 200
#define DD 64
#define H0 128
#define H1 64
#define MP 76    // MhT pitch (halfs): row term 38 dw == 6 mod 32 -> 16-way spread
#define WP 140   // W1T pitch (halfs): 70 dw == 6 mod 32 -> same

// Transposed-GEMM DIN attention, fp16 weights/activations, fp32 accum/softmax.
//   M_b = W0b - W0c + diag(q) W0d  (64x128 fp16 LDS [h][d], pitch-76)
//   layer0^T frag c -> immediately folded into 4 persistent layer1 accs
//   (outer c loop unroll 1, all reg arrays statically indexed -> ~60 VGPRs).
//   Logits -> LDS; exact softmax; v-streaming pooling.
// 512-thread blocks sharing one b: same ~41 KB LDS per block but 8 waves ->
// 3 blocks/CU = 24 waves/CU (75% cap; VGPR cap 512/80 = 6 waves/SIMD).
// R7 at 256 thr was LDS-capped at 16 waves/CU (42% observed), latency-bound.
// (512,4): VGPR budget 128; arch need ~60 -> no R2/R4-style split spills.
__global__ __launch_bounds__(512, 4)
void din_attn(const float* __restrict__ q, const float* __restrict__ k,
              const float* __restrict__ v, const int* __restrict__ mask,
              const float* __restrict__ W0, const float* __restrict__ b0,
              const float* __restrict__ W1, const float* __restrict__ b1,
              const float* __restrict__ Wf, float* __restrict__ out)
{
  const int b    = blockIdx.x;
  const int tid  = threadIdx.x;   // 0..511
  const int lane = tid & 63;
  const int wid  = tid >> 6;      // 0..7
  const int r16  = lane & 15;     // t-col within strip / A-row select
  const int g4   = lane >> 4;     // k-subgroup / D row-subgroup

  __shared__ __align__(16) _Float16 MhT[H0 * MP];   // 19.0 KB
  __shared__ __align__(16) _Float16 W1T[H1 * WP];   // 17.5 KB
  __shared__ float cbS[H0];
  __shared__ float b1S[H1];
  __shared__ float WfS[H1];
  __shared__ float sP[208];
  __shared__ float red[16];
  __shared__ float pool[512];   // cb partials, then pooling partials

  const float* qb = q + b * DD;
  const float* kb = k + (size_t)b * TT * DD;
  const float* vb = v + (size_t)b * TT * DD;
  const int*   mb = mask + b * TT;

  // ---- prologue (split across 512 threads) ----
  {
    // cb partial: h = tid&127, quarter (tid>>7) covers 16 d's
    int h = tid & 127, qtr = tid >> 7;
    float s = 0.f;
    #pragma unroll 4
    for (int i = 0; i < 16; ++i) {
      int d = qtr * 16 + i;
      s += qb[d] * (W0[d * H0 + h] + W0[(128 + d) * H0 + h]);
    }
    pool[tid] = s;
  }
  #pragma unroll 4
  for (int i = 0; i < 16; ++i) {      // M_b^T -> LDS [h][d]
    int idx = i * 512 + tid;
    int h = idx & 127, d = idx >> 7;
    float val = W0[(64 + d) * H0 + h] - W0[(128 + d) * H0 + h]
              + qb[d] * W0[(192 + d) * H0 + h];
    MhT[h * MP + d] = (_Float16)val;
  }
  #pragma unroll 4
  for (int i = 0; i < 16; ++i) {      // W1^T -> LDS [j][h]
    int idx = i * 512 + tid;
    int hh = idx >> 6, j = idx & 63;
    W1T[j * WP + hh] = (_Float16)W1[idx];
  }
  if (tid < H1) { b1S[tid] = b1[tid]; WfS[tid] = Wf[tid]; }
  __syncthreads();
  if (tid < H0)
    cbS[tid] = ((pool[tid] + pool[tid + 128])
              + (pool[tid + 256] + pool[tid + 384])) + b0[tid];

  // first strip's k issued before the barrier (trow = wid*16+r16 <= 127 < 200)
  float4 kq[4];
  {
    const int trow = wid * 16 + r16;
    #pragma unroll
    for (int m = 0; m < 4; ++m)
      kq[m] = *(const float4*)(kb + trow * DD + m * 16 + 4 * g4);
  }
  __syncthreads();

  // ---- pass 1: logits (wave w handles strips w, w+8) ----
  #pragma unroll 1
  for (int s = wid; s < 13; s += 8) {
    const int t0   = s * 16;
    const int trow = t0 + r16;
    const bool tv  = trow < TT;
    int mm = tv ? mb[trow] : -1;

    f16x4 bh[4];
    #pragma unroll
    for (int m = 0; m < 4; ++m) {
      float kf[4] = {kq[m].x, kq[m].y, kq[m].z, kq[m].w};
      #pragma unroll
      for (int j = 0; j < 4; ++j) bh[m][j] = (_Float16)kf[j];
    }
    const int sn = s + 8;
    if (sn < 13) {
      const int trn = sn * 16 + r16;
      const bool tvn = trn < TT;
      #pragma unroll
      for (int m = 0; m < 4; ++m) {
        float4 z = {0.f, 0.f, 0.f, 0.f};
        kq[m] = tvn ? *(const float4*)(kb + trn * DD + m * 16 + 4 * g4) : z;
      }
    }

    f32x4 acc1[4];
    #pragma unroll
    for (int c1 = 0; c1 < 4; ++c1) acc1[c1] = (f32x4){0.f, 0.f, 0.f, 0.f};

    // outer c loop NOT unrolled: nothing register-resident indexed by c
    #pragma unroll 1
    for (int c = 0; c < 8; ++c) {
      const _Float16* mrow = &MhT[(c * 16 + r16) * MP];
      f32x4 a0 = {0.f, 0.f, 0.f, 0.f};
      #pragma unroll
      for (int ks = 0; ks < 4; ++ks) {
        f16x4 af = *(const f16x4*)(mrow + ks * 16 + 4 * g4);
        a0 = __builtin_amdgcn_mfma_f32_16x16x16f16(af, bh[ks], a0, 0, 0, 0);
      }
      f32x4 cb4 = *(const f32x4*)(&cbS[c * 16 + 4 * g4]);
      f16x4 hf;
      #pragma unroll
      for (int r = 0; r < 4; ++r) {
        float hv = a0[r] + cb4[r];
        hf[r] = (_Float16)(hv > 0.f ? hv : 0.f);
      }
      #pragma unroll
      for (int c1 = 0; c1 < 4; ++c1) {
        f16x4 af1 = *(const f16x4*)(&W1T[(c1 * 16 + r16) * WP + c * 16 + 4 * g4]);
        acc1[c1] = __builtin_amdgcn_mfma_f32_16x16x16f16(af1, hf, acc1[c1], 0, 0, 0);
      }
    }

    float p = 0.f;
    #pragma unroll
    for (int c1 = 0; c1 < 4; ++c1) {
      f32x4 b14 = *(const f32x4*)(&b1S[c1 * 16 + 4 * g4]);
      f32x4 wf4 = *(const f32x4*)(&WfS[c1 * 16 + 4 * g4]);
      #pragma unroll
      for (int r = 0; r < 4; ++r) {
        float h1 = acc1[c1][r] + b14[r];
        h1 = h1 > 0.f ? h1 : 0.f;
        p = fmaf(h1, wf4[r], p);
      }
    }

    p += __shfl_xor(p, 16, 64);
    p += __shfl_xor(p, 32, 64);
    p = (mm == 1) ? p : (mm == 0 ? -1e30f : -2e30f);
    if (g4 == 0) sP[t0 + r16] = p;
  }
  __syncthreads();

  // ---- pass 2: exact softmax over sP[0..207] ----
  float rcpS;
  {
    float val = (tid < 208) ? sP[tid] : -3e30f;
    float mx = val;
    #pragma unroll
    for (int off = 32; off >= 1; off >>= 1) mx = fmaxf(mx, __shfl_xor(mx, off, 64));
    if (lane == 0) red[wid] = mx;
    __syncthreads();
    float M = red[0];
    #pragma unroll
    for (int w = 1; w < 8; ++w) M = fmaxf(M, red[w]);
    float e = (tid < 208) ? __expf(val - M) : 0.f;
    float se = e;
    #pragma unroll
    for (int off = 32; off >= 1; off >>= 1) se += __shfl_xor(se, off, 64);
    if (lane == 0) red[8 + wid] = se;
    __syncthreads();
    float S = 0.f;
    #pragma unroll
    for (int w = 0; w < 8; ++w) S += red[8 + w];
    rcpS = 1.f / S;
    if (tid < 208) sP[tid] = e;
  }
  __syncthreads();

  // ---- pass 3: pooling, wave w covers t in [w*26, w*26+26) ----
  {
    float o0 = 0.f, o1 = 0.f;
    const int tbase = wid * 26;
    #pragma unroll
    for (int i = 0; i < 26; i += 2) {
      int t = tbase + i;
      if (t + 1 < TT) {
        o0 = fmaf(sP[t + 0], vb[(t + 0) * DD + lane], o0);
        o1 = fmaf(sP[t + 1], vb[(t + 1) * DD + lane], o1);
      } else if (t < TT) {
        o0 = fmaf(sP[t], vb[t * DD + lane], o0);
      }
    }
    pool[wid * 64 + lane] = o0 + o1;
  }
  __syncthreads();

  if (tid < DD) {
    float acc = 0.f;
    #pragma unroll
    for (int w = 0; w < 8; ++w) acc += pool[w * 64 + tid];
    out[b * DD + tid] = acc * rcpS;
  }
}

extern "C" void kernel_launch(void* const* d_in, const int* in_sizes, int n_in,
                              void* d_out, int out_size, void* d_ws, size_t ws_size,
                              hipStream_t stream) {
  const float* q    = (const float*)d_in[0];
  const float* k    = (const float*)d_in[1];
  const float* v    = (const float*)d_in[2];
  const int*   mask = (const int*)d_in[3];
  const float* W0   = (const float*)d_in[4];
  const float* b0   = (const float*)d_in[5];
  const float* W1   = (const float*)d_in[6];
  const float* b1   = (const float*)d_in[7];
  const float* Wf   = (const float*)d_in[8];
  float* out = (float*)d_out;
  din_attn<<<dim3(NB), dim3(512), 0, stream>>>(q, k, v, mask, W0, b0, W1, b1, Wf, out);
}

// Round 9
// 162.194 us; speedup vs baseline: 1.0992x; 1.0992x over previous
//
#include <hip/hip_runtime.h>

typedef __attribute__((ext_vector_type(4))) _Float16 f16x4;
typedef __attribute__((ext_vector_type(4))) float f32x4;

#define NB 4096
#define TT 200
#define DD 64
#define H0 128
#define H1 64
#define MP 76    // MhT pitch (halfs): row term 38 dw == 6 mod 32 -> 16-way spread
#define WP 140   // W1T pitch (halfs): 70 dw == 6 mod 32 -> same

// Transposed-GEMM DIN attention, fp16 weights/activations, fp32 accum/softmax.
//   M_b = W0b - W0c + diag(q) W0d  (64x128 fp16 LDS [h][d], pitch-76)
//   layer0^T frag -> immediately folded into persistent layer1 accs.
// DUAL-STRIP per wave: strips sA=w+8*pi, sB=sA+4 computed concurrently;
// weight fragments (af, af1) shared by both -> ds_reads per strip halve and
// the two independent MFMA chains interleave (R7 was chain-latency-bound at
// 42% occupancy). Strip-slots 13-15 are dummies (masked, no store).
// Codegen rules learned R2-R7: outer loops unroll 1, all register arrays
// statically indexed, (256,3) budget, 256-thread blocks (R8's 512 regressed).
__global__ __launch_bounds__(256, 3)
void din_attn(const float* __restrict__ q, const float* __restrict__ k,
              const float* __restrict__ v, const int* __restrict__ mask,
              const float* __restrict__ W0, const float* __restrict__ b0,
              const float* __restrict__ W1, const float* __restrict__ b1,
              const float* __restrict__ Wf, float* __restrict__ out)
{
  const int b    = blockIdx.x;
  const int tid  = threadIdx.x;
  const int lane = tid & 63;
  const int wid  = tid >> 6;
  const int r16  = lane & 15;   // t-col within strip / A-row select
  const int g4   = lane >> 4;   // k-subgroup / D row-subgroup

  __shared__ __align__(16) _Float16 MhT[H0 * MP];   // 19.0 KB
  __shared__ __align__(16) _Float16 W1T[H1 * WP];   // 17.5 KB
  __shared__ float cbS[H0];
  __shared__ float b1S[H1];
  __shared__ float WfS[H1];
  __shared__ float sP[208];
  __shared__ float red[8];
  __shared__ float pool[256];   // cb partials, then pooling partials

  const float* qb = q + b * DD;
  const float* kb = k + (size_t)b * TT * DD;
  const float* vb = v + (size_t)b * TT * DD;
  const int*   mb = mask + b * TT;

  // ---- prologue ----
  {
    int h = tid & 127, half = tid >> 7;
    float s = 0.f;
    #pragma unroll 8
    for (int i = 0; i < 32; ++i) {
      int d = half * 32 + i;
      s += qb[d] * (W0[d * H0 + h] + W0[(128 + d) * H0 + h]);
    }
    pool[tid] = s;
  }
  #pragma unroll 4
  for (int i = 0; i < 32; ++i) {      // M_b^T -> LDS [h][d]
    int idx = i * 256 + tid;
    int h = idx & 127, d = idx >> 7;
    float val = W0[(64 + d) * H0 + h] - W0[(128 + d) * H0 + h]
              + qb[d] * W0[(192 + d) * H0 + h];
    MhT[h * MP + d] = (_Float16)val;
  }
  #pragma unroll 4
  for (int i = 0; i < 32; ++i) {      // W1^T -> LDS [j][h]
    int idx = i * 256 + tid;
    int hh = idx >> 6, j = idx & 63;
    W1T[j * WP + hh] = (_Float16)W1[idx];
  }
  if (tid < H1) { b1S[tid] = b1[tid]; WfS[tid] = Wf[tid]; }
  __syncthreads();
  if (tid < H0) cbS[tid] = pool[tid] + pool[tid + 128] + b0[tid];

  // preload pair 0: strips (wid, wid+4); trow <= 127 < 200, no guard
  float4 kqA[4], kqB[4];
  {
    const int trA = wid * 16 + r16;
    const int trB = trA + 64;
    #pragma unroll
    for (int m = 0; m < 4; ++m) {
      kqA[m] = *(const float4*)(kb + trA * DD + m * 16 + 4 * g4);
      kqB[m] = *(const float4*)(kb + trB * DD + m * 16 + 4 * g4);
    }
  }
  __syncthreads();

  // ---- pass 1: logits, two strips per wave per iteration ----
  #pragma unroll 1
  for (int pi = 0; pi < 2; ++pi) {
    const int sA   = wid + pi * 8;       // always a real strip (<= 11)
    const int sB   = sA + 4;             // may be dummy (13..15)
    const int t0A  = sA * 16, t0B = sB * 16;
    const int trA  = t0A + r16, trB = t0B + r16;
    const int mmA  = (trA < TT) ? mb[trA] : -1;
    const int mmB  = (trB < TT) ? mb[trB] : -1;

    // convert current k to fp16 B-fragments
    f16x4 bhA[4], bhB[4];
    #pragma unroll
    for (int m = 0; m < 4; ++m) {
      float fA[4] = {kqA[m].x, kqA[m].y, kqA[m].z, kqA[m].w};
      float fB[4] = {kqB[m].x, kqB[m].y, kqB[m].z, kqB[m].w};
      #pragma unroll
      for (int j = 0; j < 4; ++j) {
        bhA[m][j] = (_Float16)fA[j];
        bhB[m][j] = (_Float16)fB[j];
      }
    }
    // prefetch pair 1: strips (wid+8, wid+12); A side always valid (<=191)
    if (pi == 0) {
      const int trA2 = (wid + 8) * 16 + r16;
      const int trB2 = trA2 + 64;
      const bool tvB2 = trB2 < TT;
      #pragma unroll
      for (int m = 0; m < 4; ++m) {
        float4 z = {0.f, 0.f, 0.f, 0.f};
        kqA[m] = *(const float4*)(kb + trA2 * DD + m * 16 + 4 * g4);
        kqB[m] = tvB2 ? *(const float4*)(kb + trB2 * DD + m * 16 + 4 * g4) : z;
      }
    }

    f32x4 acc1A[4], acc1B[4];
    #pragma unroll
    for (int c1 = 0; c1 < 4; ++c1) {
      acc1A[c1] = (f32x4){0.f, 0.f, 0.f, 0.f};
      acc1B[c1] = (f32x4){0.f, 0.f, 0.f, 0.f};
    }

    // outer c loop NOT unrolled: nothing register-resident indexed by c
    #pragma unroll 1
    for (int c = 0; c < 8; ++c) {
      const _Float16* mrow = &MhT[(c * 16 + r16) * MP];
      f32x4 a0A = {0.f, 0.f, 0.f, 0.f};
      f32x4 a0B = {0.f, 0.f, 0.f, 0.f};
      #pragma unroll
      for (int ks = 0; ks < 4; ++ks) {
        f16x4 af = *(const f16x4*)(mrow + ks * 16 + 4 * g4);
        a0A = __builtin_amdgcn_mfma_f32_16x16x16f16(af, bhA[ks], a0A, 0, 0, 0);
        a0B = __builtin_amdgcn_mfma_f32_16x16x16f16(af, bhB[ks], a0B, 0, 0, 0);
      }
      f32x4 cb4 = *(const f32x4*)(&cbS[c * 16 + 4 * g4]);
      f16x4 hfA, hfB;
      #pragma unroll
      for (int r = 0; r < 4; ++r) {
        float hA = a0A[r] + cb4[r];
        float hB = a0B[r] + cb4[r];
        hfA[r] = (_Float16)(hA > 0.f ? hA : 0.f);
        hfB[r] = (_Float16)(hB > 0.f ? hB : 0.f);
      }
      #pragma unroll
      for (int c1 = 0; c1 < 4; ++c1) {
        f16x4 af1 = *(const f16x4*)(&W1T[(c1 * 16 + r16) * WP + c * 16 + 4 * g4]);
        acc1A[c1] = __builtin_amdgcn_mfma_f32_16x16x16f16(af1, hfA, acc1A[c1], 0, 0, 0);
        acc1B[c1] = __builtin_amdgcn_mfma_f32_16x16x16f16(af1, hfB, acc1B[c1], 0, 0, 0);
      }
    }

    float pA = 0.f, pB = 0.f;
    #pragma unroll
    for (int c1 = 0; c1 < 4; ++c1) {
      f32x4 b14 = *(const f32x4*)(&b1S[c1 * 16 + 4 * g4]);
      f32x4 wf4 = *(const f32x4*)(&WfS[c1 * 16 + 4 * g4]);
      #pragma unroll
      for (int r = 0; r < 4; ++r) {
        float hA = acc1A[c1][r] + b14[r];
        float hB = acc1B[c1][r] + b14[r];
        hA = hA > 0.f ? hA : 0.f;
        hB = hB > 0.f ? hB : 0.f;
        pA = fmaf(hA, wf4[r], pA);
        pB = fmaf(hB, wf4[r], pB);
      }
    }

    pA += __shfl_xor(pA, 16, 64);
    pA += __shfl_xor(pA, 32, 64);
    pB += __shfl_xor(pB, 16, 64);
    pB += __shfl_xor(pB, 32, 64);
    pA = (mmA == 1) ? pA : (mmA == 0 ? -1e30f : -2e30f);
    pB = (mmB == 1) ? pB : (mmB == 0 ? -1e30f : -2e30f);
    if (g4 == 0) {
      sP[t0A + r16] = pA;                       // sA <= 11 -> always in range
      if (t0B + r16 < 208) sP[t0B + r16] = pB;  // skips dummy strips 13..15
    }
  }
  __syncthreads();

  // ---- pass 2: exact softmax over sP[0..207] ----
  float rcpS;
  {
    float val = (tid < 208) ? sP[tid] : -3e30f;
    float mx = val;
    #pragma unroll
    for (int off = 32; off >= 1; off >>= 1) mx = fmaxf(mx, __shfl_xor(mx, off, 64));
    if (lane == 0) red[wid] = mx;
    __syncthreads();
    float M = fmaxf(fmaxf(red[0], red[1]), fmaxf(red[2], red[3]));
    float e = (tid < 208) ? __expf(val - M) : 0.f;
    float se = e;
    #pragma unroll
    for (int off = 32; off >= 1; off >>= 1) se += __shfl_xor(se, off, 64);
    if (lane == 0) red[4 + wid] = se;
    __syncthreads();
    rcpS = 1.f / ((red[4] + red[5]) + (red[6] + red[7]));
    if (tid < 208) sP[tid] = e;
  }
  __syncthreads();

  // ---- pass 3: pooling, wave w covers t in [w*52, w*52+52) ----
  {
    float o0 = 0.f, o1 = 0.f, o2 = 0.f, o3 = 0.f;
    const int tbase = wid * 52;
    #pragma unroll 4
    for (int i = 0; i < 52; i += 4) {
      int t = tbase + i;
      if (t + 3 < TT) {
        o0 = fmaf(sP[t + 0], vb[(t + 0) * DD + lane], o0);
        o1 = fmaf(sP[t + 1], vb[(t + 1) * DD + lane], o1);
        o2 = fmaf(sP[t + 2], vb[(t + 2) * DD + lane], o2);
        o3 = fmaf(sP[t + 3], vb[(t + 3) * DD + lane], o3);
      } else {
        #pragma unroll
        for (int j = 0; j < 4; ++j) {
          int tj = t + j;
          if (tj < TT) o0 = fmaf(sP[tj], vb[tj * DD + lane], o0);
        }
      }
    }
    pool[wid * 64 + lane] = (o0 + o1) + (o2 + o3);
  }
  __syncthreads();

  if (tid < DD)
    out[b * DD + tid] = ((pool[tid] + pool[64 + tid])
                       + (pool[128 + tid] + pool[192 + tid])) * rcpS;
}

extern "C" void kernel_launch(void* const* d_in, const int* in_sizes, int n_in,
                              void* d_out, int out_size, void* d_ws, size_t ws_size,
                              hipStream_t stream) {
  const float* q    = (const float*)d_in[0];
  const float* k    = (const float*)d_in[1];
  const float* v    = (const float*)d_in[2];
  const int*   mask = (const int*)d_in[3];
  const float* W0   = (const float*)d_in[4];
  const float* b0   = (const float*)d_in[5];
  const float* W1   = (const float*)d_in[6];
  const float* b1   = (const float*)d_in[7];
  const float* Wf   = (const float*)d_in[8];
  float* out = (float*)d_out;
  din_attn<<<dim3(NB), dim3(256), 0, stream>>>(q, k, v, mask, W0, b0, W1, b1, Wf, out);
}

// Round 10
// 157.418 us; speedup vs baseline: 1.1325x; 1.0303x over previous
//
#include <hip/hip_runtime.h>

typedef __attribute__((ext_vector_type(4))) _Float16 f16x4;
typedef __attribute__((ext_vector_type(8))) _Float16 f16x8;
typedef __attribute__((ext_vector_type(4))) float f32x4;

#define NB 4096
#define TT 200
#define DD 64
#define H0 128
#define H1 64

// ws layout (bytes)
#define WS_BC 0        // W0bcT fp16 [128][64]  = 16384 B   (W0b - W0c, transposed)
#define WS_DD 16384    // W0dT  fp16 [128][64]  = 16384 B   (W0d, transposed)
#define WS_W1 32768    // W1T LDS image fp16, XOR-swizzled [64][128] = 16384 B
#define WS_CB 49152    // cb f32 [4096][128] = 2 MB

// ---- pre-kernel A: fold W0 -> fp16 transposed parts + swizzled W1T image ----
__global__ __launch_bounds__(256)
void pre_fold(const float* __restrict__ W0, const float* __restrict__ W1,
              unsigned char* __restrict__ ws)
{
  int idx = blockIdx.x * 256 + threadIdx.x;   // grid 64 -> 16384 threads
  _Float16* bcT = (_Float16*)(ws + WS_BC);
  _Float16* ddT = (_Float16*)(ws + WS_DD);
  _Float16* w1i = (_Float16*)(ws + WS_W1);
  if (idx < 8192) {
    int h = idx >> 6, d = idx & 63;
    bcT[h * 64 + d] = (_Float16)(W0[(64 + d) * H0 + h] - W0[(128 + d) * H0 + h]);
    ddT[h * 64 + d] = (_Float16)(W0[(192 + d) * H0 + h]);
  } else {
    int i = idx - 8192;                       // 0..8191
    int hh = i >> 6, j = i & 63;
    w1i[j * 128 + (hh ^ ((j & 7) << 3))] = (_Float16)W1[hh * H1 + j];
  }
}

// ---- pre-kernel B: cb[b][h] = b0[h] + q[b] @ (W0a + W0c) ----
__global__ __launch_bounds__(256)
void pre_cb(const float* __restrict__ q, const float* __restrict__ W0,
            const float* __restrict__ b0, unsigned char* __restrict__ ws)
{
  __shared__ float WacS[DD * H0];   // 32 KB, [d][h]
  __shared__ float qS2[2][DD];
  const int tid = threadIdx.x;
  float* cb = (float*)(ws + WS_CB);

  #pragma unroll 4
  for (int i = 0; i < 32; ++i) {
    int idx = i * 256 + tid;
    int d = idx >> 7, h = idx & 127;
    WacS[idx] = W0[d * H0 + h] + W0[(128 + d) * H0 + h];
  }
  __syncthreads();

  const int half = tid >> 7, h = tid & 127;
  #pragma unroll 1
  for (int p = 0; p < 16; ++p) {
    int bpair = blockIdx.x * 32 + p * 2;      // grid 128
    if (tid < DD)              qS2[0][tid] = q[(size_t)bpair * DD + tid];
    else if (tid >= 128 && tid < 128 + DD) qS2[1][tid - 128] = q[(size_t)(bpair + 1) * DD + (tid - 128)];
    __syncthreads();
    float s = b0[h];
    #pragma unroll 8
    for (int d = 0; d < DD; ++d) s = fmaf(qS2[half][d], WacS[d * H0 + h], s);
    cb[(size_t)(bpair + half) * H0 + h] = s;
    __syncthreads();
  }
}

// ---- main kernel ----
// Transposed-GEMM DIN attention, fp16 weights/activations, fp32 accum/softmax.
//   MhT[h][d] = W0bcT + q[d]*W0dT  (built from prefolded fp16 ws, XOR-swizzled)
//   layer0^T frag c -> immediately folded into 4 persistent layer1 accs.
//   cb / W1T image prefolded in ws -> prologue is ~25 loads/thread (was ~190).
// Codegen rules (R2-R9): outer s-loop unroll 1, c-loop unroll 2 (no reg array
// indexed by c), all reg arrays statically indexed, (256,3), 256-thr blocks.
__global__ __launch_bounds__(256, 3)
void din_attn(const float* __restrict__ q, const float* __restrict__ k,
              const float* __restrict__ v, const int* __restrict__ mask,
              const float* __restrict__ b1, const float* __restrict__ Wf,
              const unsigned char* __restrict__ ws, float* __restrict__ out)
{
  const int b    = blockIdx.x;
  const int tid  = threadIdx.x;
  const int lane = tid & 63;
  const int wid  = tid >> 6;
  const int r16  = lane & 15;
  const int g4   = lane >> 4;

  __shared__ __align__(16) _Float16 MhT[H0 * 64];   // 16 KB, XOR-swizzled
  __shared__ __align__(16) _Float16 W1T[H1 * 128];  // 16 KB, XOR-swizzled
  __shared__ float qS[DD];
  __shared__ float cbS[H0];
  __shared__ float b1S[H1];
  __shared__ float WfS[H1];
  __shared__ float sP[208];
  __shared__ float red[8];
  __shared__ float pool[256];

  const float* qb = q + b * DD;
  const float* kb = k + (size_t)b * TT * DD;
  const float* vb = v + (size_t)b * TT * DD;
  const int*   mb = mask + b * TT;

  // ---- prologue: light staging from prefolded ws ----
  {
    const uint4* src = (const uint4*)(ws + WS_W1);
    uint4* dst = (uint4*)W1T;
    #pragma unroll
    for (int i = 0; i < 4; ++i) dst[i * 256 + tid] = src[i * 256 + tid];
  }
  if (tid < DD) qS[tid] = qb[tid];
  if (tid < H0) cbS[tid] = ((const float*)(ws + WS_CB))[(size_t)b * H0 + tid];
  if (tid >= H0 && tid < H0 + H1) b1S[tid - H0] = b1[tid - H0];
  if (tid >= H0 + H1 && tid < H0 + 2 * H1) WfS[tid - H0 - H1] = Wf[tid - H0 - H1];
  __syncthreads();   // qS ready for M build

  // M_b build: thread = (h4 = tid>>3 -> 4 rows, dblk = tid&7 -> 8 d's)
  {
    const _Float16* bcT = (const _Float16*)(ws + WS_BC);
    const _Float16* ddT = (const _Float16*)(ws + WS_DD);
    const int dblk = (tid & 7) * 8;
    const int h4 = (tid >> 3) * 4;
    float q8[8];
    #pragma unroll
    for (int j = 0; j < 8; ++j) q8[j] = qS[dblk + j];
    #pragma unroll
    for (int hi = 0; hi < 4; ++hi) {
      const int h = h4 + hi;
      f16x8 bc8 = *(const f16x8*)(bcT + h * 64 + dblk);
      f16x8 dd8 = *(const f16x8*)(ddT + h * 64 + dblk);
      f16x8 o8;
      #pragma unroll
      for (int j = 0; j < 8; ++j)
        o8[j] = (_Float16)((float)bc8[j] + q8[j] * (float)dd8[j]);
      *(f16x8*)(&MhT[h * 64 + (dblk ^ ((h & 7) << 3))]) = o8;
    }
  }

  // first strip's k issued before the barrier
  float4 kq[4];
  {
    const int trow = wid * 16 + r16;
    #pragma unroll
    for (int m = 0; m < 4; ++m)
      kq[m] = *(const float4*)(kb + trow * DD + m * 16 + 4 * g4);
  }
  __syncthreads();

  const int sw = (r16 & 7) << 3;   // XOR key, row-independent across c

  // ---- pass 1: logits ----
  #pragma unroll 1
  for (int s = wid; s < 13; s += 4) {
    const int t0   = s * 16;
    const int trow = t0 + r16;
    int mm = (trow < TT) ? mb[trow] : -1;

    f16x4 bh[4];
    #pragma unroll
    for (int m = 0; m < 4; ++m) {
      float kf[4] = {kq[m].x, kq[m].y, kq[m].z, kq[m].w};
      #pragma unroll
      for (int j = 0; j < 4; ++j) bh[m][j] = (_Float16)kf[j];
    }
    const int sn = s + 4;
    if (sn < 13) {
      const int trn = sn * 16 + r16;
      const bool tvn = trn < TT;
      #pragma unroll
      for (int m = 0; m < 4; ++m) {
        float4 z = {0.f, 0.f, 0.f, 0.f};
        kq[m] = tvn ? *(const float4*)(kb + trn * DD + m * 16 + 4 * g4) : z;
      }
    }

    f32x4 acc1[4];
    #pragma unroll
    for (int c1 = 0; c1 < 4; ++c1) acc1[c1] = (f32x4){0.f, 0.f, 0.f, 0.f};

    // unroll 2: overlaps c/c+1 ds_reads with MFMAs; no reg array indexed by c
    #pragma unroll 2
    for (int c = 0; c < 8; ++c) {
      const _Float16* mbase = &MhT[(c * 16 + r16) * 64];
      f32x4 a0 = {0.f, 0.f, 0.f, 0.f};
      #pragma unroll
      for (int ks = 0; ks < 4; ++ks) {
        f16x4 af = *(const f16x4*)(mbase + ((ks * 16 + 4 * g4) ^ sw));
        a0 = __builtin_amdgcn_mfma_f32_16x16x16f16(af, bh[ks], a0, 0, 0, 0);
      }
      f32x4 cb4 = *(const f32x4*)(&cbS[c * 16 + 4 * g4]);
      f16x4 hf;
      #pragma unroll
      for (int r = 0; r < 4; ++r) {
        float hv = a0[r] + cb4[r];
        hf[r] = (_Float16)(hv > 0.f ? hv : 0.f);
      }
      #pragma unroll
      for (int c1 = 0; c1 < 4; ++c1) {
        f16x4 af1 = *(const f16x4*)(&W1T[(c1 * 16 + r16) * 128 + ((c * 16 + 4 * g4) ^ sw)]);
        acc1[c1] = __builtin_amdgcn_mfma_f32_16x16x16f16(af1, hf, acc1[c1], 0, 0, 0);
      }
    }

    float p = 0.f;
    #pragma unroll
    for (int c1 = 0; c1 < 4; ++c1) {
      f32x4 b14 = *(const f32x4*)(&b1S[c1 * 16 + 4 * g4]);
      f32x4 wf4 = *(const f32x4*)(&WfS[c1 * 16 + 4 * g4]);
      #pragma unroll
      for (int r = 0; r < 4; ++r) {
        float h1 = acc1[c1][r] + b14[r];
        h1 = h1 > 0.f ? h1 : 0.f;
        p = fmaf(h1, wf4[r], p);
      }
    }

    p += __shfl_xor(p, 16, 64);
    p += __shfl_xor(p, 32, 64);
    p = (mm == 1) ? p : (mm == 0 ? -1e30f : -2e30f);
    if (g4 == 0) sP[t0 + r16] = p;
  }
  __syncthreads();

  // ---- pass 2: exact softmax over sP[0..207] ----
  float rcpS;
  {
    float val = (tid < 208) ? sP[tid] : -3e30f;
    float mx = val;
    #pragma unroll
    for (int off = 32; off >= 1; off >>= 1) mx = fmaxf(mx, __shfl_xor(mx, off, 64));
    if (lane == 0) red[wid] = mx;
    __syncthreads();
    float M = fmaxf(fmaxf(red[0], red[1]), fmaxf(red[2], red[3]));
    float e = (tid < 208) ? __expf(val - M) : 0.f;
    float se = e;
    #pragma unroll
    for (int off = 32; off >= 1; off >>= 1) se += __shfl_xor(se, off, 64);
    if (lane == 0) red[4 + wid] = se;
    __syncthreads();
    rcpS = 1.f / ((red[4] + red[5]) + (red[6] + red[7]));
    if (tid < 208) sP[tid] = e;
  }
  __syncthreads();

  // ---- pass 3: pooling, wave w covers t in [w*52, w*52+52) ----
  {
    float o0 = 0.f, o1 = 0.f, o2 = 0.f, o3 = 0.f;
    const int tbase = wid * 52;
    #pragma unroll 4
    for (int i = 0; i < 52; i += 4) {
      int t = tbase + i;
      if (t + 3 < TT) {
        o0 = fmaf(sP[t + 0], vb[(t + 0) * DD + lane], o0);
        o1 = fmaf(sP[t + 1], vb[(t + 1) * DD + lane], o1);
        o2 = fmaf(sP[t + 2], vb[(t + 2) * DD + lane], o2);
        o3 = fmaf(sP[t + 3], vb[(t + 3) * DD + lane], o3);
      } else {
        #pragma unroll
        for (int j = 0; j < 4; ++j) {
          int tj = t + j;
          if (tj < TT) o0 = fmaf(sP[tj], vb[tj * DD + lane], o0);
        }
      }
    }
    pool[wid * 64 + lane] = (o0 + o1) + (o2 + o3);
  }
  __syncthreads();

  if (tid < DD)
    out[b * DD + tid] = ((pool[tid] + pool[64 + tid])
                       + (pool[128 + tid] + pool[192 + tid])) * rcpS;
}

extern "C" void kernel_launch(void* const* d_in, const int* in_sizes, int n_in,
                              void* d_out, int out_size, void* d_ws, size_t ws_size,
                              hipStream_t stream) {
  const float* q    = (const float*)d_in[0];
  const float* k    = (const float*)d_in[1];
  const float* v    = (const float*)d_in[2];
  const int*   mask = (const int*)d_in[3];
  const float* W0   = (const float*)d_in[4];
  const float* b0   = (const float*)d_in[5];
  const float* W1   = (const float*)d_in[6];
  const float* b1   = (const float*)d_in[7];
  const float* Wf   = (const float*)d_in[8];
  float* out = (float*)d_out;
  unsigned char* ws = (unsigned char*)d_ws;

  pre_fold<<<dim3(64), dim3(256), 0, stream>>>(W0, W1, ws);
  pre_cb<<<dim3(128), dim3(256), 0, stream>>>(q, W0, b0, ws);
  din_attn<<<dim3(NB), dim3(256), 0, stream>>>(q, k, v, mask, b1, Wf, ws, out);
}

// Round 11
// 139.009 us; speedup vs baseline: 1.2825x; 1.1324x over previous
//
#include <hip/hip_runtime.h>

typedef __attribute__((ext_vector_type(4))) _Float16 f16x4;
typedef __attribute__((ext_vector_type(8))) _Float16 f16x8;
typedef __attribute__((ext_vector_type(4))) float f32x4;

#define NB 4096
#define TT 200
#define DD 64
#define H0 128
#define H1 64
#define MP 72    // MhT pitch (halfs): 144B rows, 16B-aligned, 36dw==4 mod 32 (2-way free)
#define WP 136   // W1phi pitch (halfs): 272B rows, 16B-aligned, 68dw==4 mod 32

// ws layout (bytes)
#define WS_BC 0        // W0bcT fp16 [128][64] = 16384 B  (W0b - W0c, transposed)
#define WS_DD 16384    // W0dT  fp16 [128][64] = 16384 B  (W0d, transposed)
#define WS_W1 32768    // W1phi fp16 [64][136] = 17408 B  (phi-permuted, pitched)
#define WS_CB 50176    // cb f32 [4096][128] = 2 MB

// ---- pre-kernel A: fold W0 -> fp16 transposed parts + phi-permuted W1 image ----
// phi(g4,jj) = 4*g4 + (jj&3) + 16*(jj>>2): the k-labeling that matches the
// layer0 D-fragment layout, so layer1's A-frag is ONE b128 per (c1,m).
__global__ __launch_bounds__(256)
void pre_fold(const float* __restrict__ W0, const float* __restrict__ W1,
              unsigned char* __restrict__ ws)
{
  int idx = blockIdx.x * 256 + threadIdx.x;   // grid 64 -> 16384 threads
  _Float16* bcT  = (_Float16*)(ws + WS_BC);
  _Float16* ddT  = (_Float16*)(ws + WS_DD);
  _Float16* w1p  = (_Float16*)(ws + WS_W1);
  if (idx < 8192) {
    int h = idx >> 6, d = idx & 63;
    bcT[h * 64 + d] = (_Float16)(W0[(64 + d) * H0 + h] - W0[(128 + d) * H0 + h]);
    ddT[h * 64 + d] = (_Float16)(W0[(192 + d) * H0 + h]);
  } else {
    int i = idx - 8192;                       // 0..8191
    int jrow = i >> 7, p = i & 127;           // p = m*32 + g4*8 + jj
    int m = p >> 5, g4p = (p >> 3) & 3, jj = p & 7;
    int h = 32 * m + 16 * (jj >> 2) + 4 * g4p + (jj & 3);
    w1p[jrow * WP + p] = (_Float16)W1[h * H1 + jrow];
  }
}

// ---- pre-kernel B: cb[b][h] = b0[h] + q[b] @ (W0a + W0c) ----
__global__ __launch_bounds__(256)
void pre_cb(const float* __restrict__ q, const float* __restrict__ W0,
            const float* __restrict__ b0, unsigned char* __restrict__ ws)
{
  __shared__ float WacS[DD * H0];   // 32 KB, [d][h]
  __shared__ float qS2[2][DD];
  const int tid = threadIdx.x;
  float* cb = (float*)(ws + WS_CB);

  #pragma unroll 4
  for (int i = 0; i < 32; ++i) {
    int idx = i * 256 + tid;
    int d = idx >> 7, h = idx & 127;
    WacS[idx] = W0[d * H0 + h] + W0[(128 + d) * H0 + h];
  }
  __syncthreads();

  const int half = tid >> 7, h = tid & 127;
  #pragma unroll 1
  for (int p = 0; p < 16; ++p) {
    int bpair = blockIdx.x * 32 + p * 2;      // grid 128
    if (tid < DD) qS2[0][tid] = q[(size_t)bpair * DD + tid];
    else if (tid >= 128 && tid < 128 + DD) qS2[1][tid - 128] = q[(size_t)(bpair + 1) * DD + (tid - 128)];
    __syncthreads();
    float s = b0[h];
    #pragma unroll 8
    for (int d = 0; d < DD; ++d) s = fmaf(qS2[half][d], WacS[d * H0 + h], s);
    cb[(size_t)(bpair + half) * H0 + h] = s;
    __syncthreads();
  }
}

// ---- main kernel ----
// Transposed-GEMM DIN attention, fp16 weights/acts, fp32 accum/softmax, with
// BOTH layers on mfma_f32_16x16x32_f16 (32 MFMA/strip vs 64 with x16; a0
// chain 2, acc1 chain 4). k-relabeling correctness: k is contracted, and A/B
// hardware lane->k maps are identical, so any bijection applied to both sides
// is exact -- layer0 uses natural labels, layer1 uses phi (= D-frag layout).
// Codegen rules (R2-R10): outer loops unroll 1, reg arrays statically indexed
// (full-unroll inner), (256,3), 256-thr blocks, pitched (not XOR) LDS.
__global__ __launch_bounds__(256, 3)
void din_attn(const float* __restrict__ q, const float* __restrict__ k,
              const float* __restrict__ v, const int* __restrict__ mask,
              const float* __restrict__ b1, const float* __restrict__ Wf,
              const unsigned char* __restrict__ ws, float* __restrict__ out)
{
  const int b    = blockIdx.x;
  const int tid  = threadIdx.x;
  const int lane = tid & 63;
  const int wid  = tid >> 6;
  const int r16  = lane & 15;
  const int g4   = lane >> 4;

  __shared__ __align__(16) _Float16 MhT[H0 * MP];   // 18432 B
  __shared__ __align__(16) _Float16 W1p[H1 * WP];   // 17408 B
  __shared__ float qS[DD];
  __shared__ float cbS[H0];
  __shared__ float b1S[H1];
  __shared__ float WfS[H1];
  __shared__ float sP[208];
  __shared__ float red[8];
  __shared__ float pool[256];

  const float* qb = q + b * DD;
  const float* kb = k + (size_t)b * TT * DD;
  const float* vb = v + (size_t)b * TT * DD;
  const int*   mb = mask + b * TT;

  // ---- prologue: light staging from prefolded ws ----
  {
    const uint4* src = (const uint4*)(ws + WS_W1);
    uint4* dst = (uint4*)W1p;
    #pragma unroll
    for (int i = 0; i < 5; ++i) {
      int idx = i * 256 + tid;
      if (idx < (H1 * WP * 2) / 16) dst[idx] = src[idx];
    }
  }
  if (tid < DD) qS[tid] = qb[tid];
  if (tid < H0) cbS[tid] = ((const float*)(ws + WS_CB))[(size_t)b * H0 + tid];
  if (tid >= H0 && tid < H0 + H1) b1S[tid - H0] = b1[tid - H0];
  if (tid >= H0 + H1 && tid < H0 + 2 * H1) WfS[tid - H0 - H1] = Wf[tid - H0 - H1];
  __syncthreads();   // qS ready for M build

  // M_b build: thread = (h4 = (tid>>3)*4 rows, dblk = (tid&7)*8 d's)
  {
    const _Float16* bcT = (const _Float16*)(ws + WS_BC);
    const _Float16* ddT = (const _Float16*)(ws + WS_DD);
    const int dblk = (tid & 7) * 8;
    const int h4 = (tid >> 3) * 4;
    float q8[8];
    #pragma unroll
    for (int j = 0; j < 8; ++j) q8[j] = qS[dblk + j];
    #pragma unroll
    for (int hi = 0; hi < 4; ++hi) {
      const int h = h4 + hi;
      f16x8 bc8 = *(const f16x8*)(bcT + h * 64 + dblk);
      f16x8 dd8 = *(const f16x8*)(ddT + h * 64 + dblk);
      f16x8 o8;
      #pragma unroll
      for (int j = 0; j < 8; ++j)
        o8[j] = (_Float16)((float)bc8[j] + q8[j] * (float)dd8[j]);
      *(f16x8*)(&MhT[h * MP + dblk]) = o8;
    }
  }

  // first strip's k issued before the barrier; d-offsets for x32 B-frags
  const int dof = 8 * g4;
  float4 kq[4];
  {
    const int trow = wid * 16 + r16;
    kq[0] = *(const float4*)(kb + trow * DD + dof);
    kq[1] = *(const float4*)(kb + trow * DD + dof + 4);
    kq[2] = *(const float4*)(kb + trow * DD + 32 + dof);
    kq[3] = *(const float4*)(kb + trow * DD + 32 + dof + 4);
  }
  __syncthreads();

  // ---- pass 1: logits ----
  #pragma unroll 1
  for (int s = wid; s < 13; s += 4) {
    const int t0   = s * 16;
    const int trow = t0 + r16;
    int mm = (trow < TT) ? mb[trow] : -1;

    // B-frags (natural k-labels d = ks*32 + 8*g4 + j)
    f16x8 bh0, bh1;
    {
      float f0[8] = {kq[0].x, kq[0].y, kq[0].z, kq[0].w,
                     kq[1].x, kq[1].y, kq[1].z, kq[1].w};
      float f1[8] = {kq[2].x, kq[2].y, kq[2].z, kq[2].w,
                     kq[3].x, kq[3].y, kq[3].z, kq[3].w};
      #pragma unroll
      for (int j = 0; j < 8; ++j) {
        bh0[j] = (_Float16)f0[j];
        bh1[j] = (_Float16)f1[j];
      }
    }
    // prefetch next strip's k
    const int sn = s + 4;
    if (sn < 13) {
      const int trn = sn * 16 + r16;
      if (trn < TT) {
        kq[0] = *(const float4*)(kb + trn * DD + dof);
        kq[1] = *(const float4*)(kb + trn * DD + dof + 4);
        kq[2] = *(const float4*)(kb + trn * DD + 32 + dof);
        kq[3] = *(const float4*)(kb + trn * DD + 32 + dof + 4);
      } else {
        float4 z = {0.f, 0.f, 0.f, 0.f};
        kq[0] = z; kq[1] = z; kq[2] = z; kq[3] = z;
      }
    }

    f32x4 acc1[4];
    #pragma unroll
    for (int c1 = 0; c1 < 4; ++c1) acc1[c1] = (f32x4){0.f, 0.f, 0.f, 0.f};

    // m-loop over 32-row h-blocks; nothing register-resident indexed by m
    #pragma unroll 1
    for (int m = 0; m < 4; ++m) {
      const _Float16* rowE = &MhT[((2 * m) * 16 + r16) * MP];
      const _Float16* rowO = rowE + 16 * MP;
      // layer0 even c-block (rows 32m+4g4+r)
      f16x8 afE0 = *(const f16x8*)(rowE + dof);
      f16x8 afE1 = *(const f16x8*)(rowE + 32 + dof);
      f32x4 a0e = {0.f, 0.f, 0.f, 0.f};
      a0e = __builtin_amdgcn_mfma_f32_16x16x32_f16(afE0, bh0, a0e, 0, 0, 0);
      a0e = __builtin_amdgcn_mfma_f32_16x16x32_f16(afE1, bh1, a0e, 0, 0, 0);
      // layer0 odd c-block (rows 32m+16+4g4+r)
      f16x8 afO0 = *(const f16x8*)(rowO + dof);
      f16x8 afO1 = *(const f16x8*)(rowO + 32 + dof);
      f32x4 a0o = {0.f, 0.f, 0.f, 0.f};
      a0o = __builtin_amdgcn_mfma_f32_16x16x32_f16(afO0, bh0, a0o, 0, 0, 0);
      a0o = __builtin_amdgcn_mfma_f32_16x16x32_f16(afO1, bh1, a0o, 0, 0, 0);

      f32x4 cbe = *(const f32x4*)(&cbS[(2 * m) * 16 + 4 * g4]);
      f32x4 cbo = *(const f32x4*)(&cbS[(2 * m) * 16 + 16 + 4 * g4]);
      f16x8 hf;   // phi-layout: j<4 -> even block regs, j>=4 -> odd block regs
      #pragma unroll
      for (int r = 0; r < 4; ++r) {
        float he = a0e[r] + cbe[r];
        float ho = a0o[r] + cbo[r];
        hf[r]     = (_Float16)(he > 0.f ? he : 0.f);
        hf[4 + r] = (_Float16)(ho > 0.f ? ho : 0.f);
      }
      // layer1: A phi-permuted in LDS -> one b128 per (c1, m)
      #pragma unroll
      for (int c1 = 0; c1 < 4; ++c1) {
        f16x8 af1 = *(const f16x8*)(&W1p[(c1 * 16 + r16) * WP + m * 32 + dof]);
        acc1[c1] = __builtin_amdgcn_mfma_f32_16x16x32_f16(af1, hf, acc1[c1], 0, 0, 0);
      }
    }

    float p = 0.f;
    #pragma unroll
    for (int c1 = 0; c1 < 4; ++c1) {
      f32x4 b14 = *(const f32x4*)(&b1S[c1 * 16 + 4 * g4]);
      f32x4 wf4 = *(const f32x4*)(&WfS[c1 * 16 + 4 * g4]);
      #pragma unroll
      for (int r = 0; r < 4; ++r) {
        float h1 = acc1[c1][r] + b14[r];
        h1 = h1 > 0.f ? h1 : 0.f;
        p = fmaf(h1, wf4[r], p);
      }
    }

    p += __shfl_xor(p, 16, 64);
    p += __shfl_xor(p, 32, 64);
    p = (mm == 1) ? p : (mm == 0 ? -1e30f : -2e30f);
    if (g4 == 0) sP[t0 + r16] = p;
  }
  __syncthreads();

  // ---- pass 2: exact softmax over sP[0..207] ----
  float rcpS;
  {
    float val = (tid < 208) ? sP[tid] : -3e30f;
    float mx = val;
    #pragma unroll
    for (int off = 32; off >= 1; off >>= 1) mx = fmaxf(mx, __shfl_xor(mx, off, 64));
    if (lane == 0) red[wid] = mx;
    __syncthreads();
    float M = fmaxf(fmaxf(red[0], red[1]), fmaxf(red[2], red[3]));
    float e = (tid < 208) ? __expf(val - M) : 0.f;
    float se = e;
    #pragma unroll
    for (int off = 32; off >= 1; off >>= 1) se += __shfl_xor(se, off, 64);
    if (lane == 0) red[4 + wid] = se;
    __syncthreads();
    rcpS = 1.f / ((red[4] + red[5]) + (red[6] + red[7]));
    if (tid < 208) sP[tid] = e;
  }
  __syncthreads();

  // ---- pass 3: pooling, wave w covers t in [w*52, w*52+52) ----
  {
    float o0 = 0.f, o1 = 0.f, o2 = 0.f, o3 = 0.f;
    const int tbase = wid * 52;
    #pragma unroll 4
    for (int i = 0; i < 52; i += 4) {
      int t = tbase + i;
      if (t + 3 < TT) {
        o0 = fmaf(sP[t + 0], vb[(t + 0) * DD + lane], o0);
        o1 = fmaf(sP[t + 1], vb[(t + 1) * DD + lane], o1);
        o2 = fmaf(sP[t + 2], vb[(t + 2) * DD + lane], o2);
        o3 = fmaf(sP[t + 3], vb[(t + 3) * DD + lane], o3);
      } else {
        #pragma unroll
        for (int j = 0; j < 4; ++j) {
          int tj = t + j;
          if (tj < TT) o0 = fmaf(sP[tj], vb[tj * DD + lane], o0);
        }
      }
    }
    pool[wid * 64 + lane] = (o0 + o1) + (o2 + o3);
  }
  __syncthreads();

  if (tid < DD)
    out[b * DD + tid] = ((pool[tid] + pool[64 + tid])
                       + (pool[128 + tid] + pool[192 + tid])) * rcpS;
}

extern "C" void kernel_launch(void* const* d_in, const int* in_sizes, int n_in,
                              void* d_out, int out_size, void* d_ws, size_t ws_size,
                              hipStream_t stream) {
  const float* q    = (const float*)d_in[0];
  const float* k    = (const float*)d_in[1];
  const float* v    = (const float*)d_in[2];
  const int*   mask = (const int*)d_in[3];
  const float* W0   = (const float*)d_in[4];
  const float* b0   = (const float*)d_in[5];
  const float* W1   = (const float*)d_in[6];
  const float* b1   = (const float*)d_in[7];
  const float* Wf   = (const float*)d_in[8];
  float* out = (float*)d_out;
  unsigned char* ws = (unsigned char*)d_ws;

  pre_fold<<<dim3(64), dim3(256), 0, stream>>>(W0, W1, ws);
  pre_cb<<<dim3(128), dim3(256), 0, stream>>>(q, W0, b0, ws);
  din_attn<<<dim3(NB), dim3(256), 0, stream>>>(q, k, v, mask, b1, Wf, ws, out);
}

// Round 12
// 124.263 us; speedup vs baseline: 1.4347x; 1.1187x over previous
//
#include <hip/hip_runtime.h>

typedef __attribute__((ext_vector_type(4))) _Float16 f16x4;
typedef __attribute__((ext_vector_type(8))) _Float16 f16x8;
typedef __attribute__((ext_vector_type(4))) float f32x4;

#define NB 4096
#define TT 200
#define DD 64
#define H0 128
#define H1 64
#define MP 72    // MhT pitch (halfs): 144B rows, 16B-aligned, 36dw==4 mod 32 (2-way free)
#define WP 136   // W1phi pitch (halfs): 272B rows, 16B-aligned, 68dw==4 mod 32

// ws layout (bytes)
#define WS_BC 0        // W0bcT fp16 [128][64] = 16384 B  (W0b - W0c, transposed)
#define WS_DD 16384    // W0dT  fp16 [128][64] = 16384 B  (W0d, transposed)
#define WS_W1 32768    // W1phi fp16 [64][136] = 17408 B  (phi-permuted, pitched)
#define WS_CB 50176    // cb f32 [4096][128] = 2 MB

// ---- pre-kernel A: fold W0 -> fp16 transposed parts + phi-permuted W1 image ----
// phi(g4,jj) = 4*g4 + (jj&3) + 16*(jj>>2): the k-labeling that matches the
// layer0 D-fragment layout, so layer1's A-frag is ONE b128 per (c1,m).
__global__ __launch_bounds__(256)
void pre_fold(const float* __restrict__ W0, const float* __restrict__ W1,
              unsigned char* __restrict__ ws)
{
  int idx = blockIdx.x * 256 + threadIdx.x;   // grid 64 -> 16384 threads
  _Float16* bcT  = (_Float16*)(ws + WS_BC);
  _Float16* ddT  = (_Float16*)(ws + WS_DD);
  _Float16* w1p  = (_Float16*)(ws + WS_W1);
  if (idx < 8192) {
    int h = idx >> 6, d = idx & 63;
    bcT[h * 64 + d] = (_Float16)(W0[(64 + d) * H0 + h] - W0[(128 + d) * H0 + h]);
    ddT[h * 64 + d] = (_Float16)(W0[(192 + d) * H0 + h]);
  } else {
    int i = idx - 8192;                       // 0..8191
    int jrow = i >> 7, p = i & 127;           // p = m*32 + g4*8 + jj
    int m = p >> 5, g4p = (p >> 3) & 3, jj = p & 7;
    int h = 32 * m + 16 * (jj >> 2) + 4 * g4p + (jj & 3);
    w1p[jrow * WP + p] = (_Float16)W1[h * H1 + jrow];
  }
}

// ---- pre-kernel B: cb[b][h] = b0[h] + q[b] @ (W0a + W0c) ----
__global__ __launch_bounds__(256)
void pre_cb(const float* __restrict__ q, const float* __restrict__ W0,
            const float* __restrict__ b0, unsigned char* __restrict__ ws)
{
  __shared__ float WacS[DD * H0];   // 32 KB, [d][h]
  __shared__ float qS2[2][DD];
  const int tid = threadIdx.x;
  float* cb = (float*)(ws + WS_CB);

  #pragma unroll 4
  for (int i = 0; i < 32; ++i) {
    int idx = i * 256 + tid;
    int d = idx >> 7, h = idx & 127;
    WacS[idx] = W0[d * H0 + h] + W0[(128 + d) * H0 + h];
  }
  __syncthreads();

  const int half = tid >> 7, h = tid & 127;
  #pragma unroll 1
  for (int p = 0; p < 16; ++p) {
    int bpair = blockIdx.x * 32 + p * 2;      // grid 128
    if (tid < DD) qS2[0][tid] = q[(size_t)bpair * DD + tid];
    else if (tid >= 128 && tid < 128 + DD) qS2[1][tid - 128] = q[(size_t)(bpair + 1) * DD + (tid - 128)];
    __syncthreads();
    float s = b0[h];
    #pragma unroll 8
    for (int d = 0; d < DD; ++d) s = fmaf(qS2[half][d], WacS[d * H0 + h], s);
    cb[(size_t)(bpair + half) * H0 + h] = s;
    __syncthreads();
  }
}

// ---- main kernel ----
// Transposed-GEMM DIN attention, fp16 weights/acts, fp32 accum/softmax, both
// layers on mfma_f32_16x16x32_f16 (k-relabeling: layer1 uses phi = D-frag
// layout; exact since k is contracted and A/B lane->k maps are identical).
// R12: pass-3 pooling vectorized -- lane=(tg,dq), float4 v loads (1 KB/wave
// per instr, 13 per thread instead of 52 scalars) + shfl-reduce over tg; mask
// staged in LDS. R11's pass-3 scalar-load latency chain was the dominant
// unmodeled stall (block slot ~26 us vs ~5 us modeled work, all pipes <25%).
// Codegen rules (R2-R10): outer loops unroll 1, reg arrays statically indexed,
// (256,3), 256-thr blocks, pitched (not XOR) LDS.
__global__ __launch_bounds__(256, 3)
void din_attn(const float* __restrict__ q, const float* __restrict__ k,
              const float* __restrict__ v, const int* __restrict__ mask,
              const float* __restrict__ b1, const float* __restrict__ Wf,
              const unsigned char* __restrict__ ws, float* __restrict__ out)
{
  const int b    = blockIdx.x;
  const int tid  = threadIdx.x;
  const int lane = tid & 63;
  const int wid  = tid >> 6;
  const int r16  = lane & 15;
  const int g4   = lane >> 4;

  __shared__ __align__(16) _Float16 MhT[H0 * MP];   // 18432 B
  __shared__ __align__(16) _Float16 W1p[H1 * WP];   // 17408 B
  __shared__ float qS[DD];
  __shared__ float cbS[H0];
  __shared__ float b1S[H1];
  __shared__ float WfS[H1];
  __shared__ float sP[208];
  __shared__ int   sM[TT];
  __shared__ float red[8];
  __shared__ float pool[256];

  const float* qb = q + b * DD;
  const float* kb = k + (size_t)b * TT * DD;
  const float* vb = v + (size_t)b * TT * DD;
  const int*   mb = mask + b * TT;

  // ---- prologue: light staging from prefolded ws ----
  {
    const uint4* src = (const uint4*)(ws + WS_W1);
    uint4* dst = (uint4*)W1p;
    #pragma unroll
    for (int i = 0; i < 5; ++i) {
      int idx = i * 256 + tid;
      if (idx < (H1 * WP * 2) / 16) dst[idx] = src[idx];
    }
  }
  if (tid < DD) qS[tid] = qb[tid];
  if (tid < TT) sM[tid] = mb[tid];
  if (tid < H0) cbS[tid] = ((const float*)(ws + WS_CB))[(size_t)b * H0 + tid];
  if (tid >= H0 && tid < H0 + H1) b1S[tid - H0] = b1[tid - H0];
  if (tid >= H0 + H1 && tid < H0 + 2 * H1) WfS[tid - H0 - H1] = Wf[tid - H0 - H1];
  __syncthreads();   // qS ready for M build

  // M_b build: thread = (h4 = (tid>>3)*4 rows, dblk = (tid&7)*8 d's)
  {
    const _Float16* bcT = (const _Float16*)(ws + WS_BC);
    const _Float16* ddT = (const _Float16*)(ws + WS_DD);
    const int dblk = (tid & 7) * 8;
    const int h4 = (tid >> 3) * 4;
    float q8[8];
    #pragma unroll
    for (int j = 0; j < 8; ++j) q8[j] = qS[dblk + j];
    #pragma unroll
    for (int hi = 0; hi < 4; ++hi) {
      const int h = h4 + hi;
      f16x8 bc8 = *(const f16x8*)(bcT + h * 64 + dblk);
      f16x8 dd8 = *(const f16x8*)(ddT + h * 64 + dblk);
      f16x8 o8;
      #pragma unroll
      for (int j = 0; j < 8; ++j)
        o8[j] = (_Float16)((float)bc8[j] + q8[j] * (float)dd8[j]);
      *(f16x8*)(&MhT[h * MP + dblk]) = o8;
    }
  }

  // first strip's k issued before the barrier; d-offsets for x32 B-frags
  const int dof = 8 * g4;
  float4 kq[4];
  {
    const int trow = wid * 16 + r16;
    kq[0] = *(const float4*)(kb + trow * DD + dof);
    kq[1] = *(const float4*)(kb + trow * DD + dof + 4);
    kq[2] = *(const float4*)(kb + trow * DD + 32 + dof);
    kq[3] = *(const float4*)(kb + trow * DD + 32 + dof + 4);
  }
  __syncthreads();

  // ---- pass 1: logits ----
  #pragma unroll 1
  for (int s = wid; s < 13; s += 4) {
    const int t0   = s * 16;
    const int trow = t0 + r16;
    int mm = (trow < TT) ? sM[trow] : -1;

    // B-frags (natural k-labels d = ks*32 + 8*g4 + j)
    f16x8 bh0, bh1;
    {
      float f0[8] = {kq[0].x, kq[0].y, kq[0].z, kq[0].w,
                     kq[1].x, kq[1].y, kq[1].z, kq[1].w};
      float f1[8] = {kq[2].x, kq[2].y, kq[2].z, kq[2].w,
                     kq[3].x, kq[3].y, kq[3].z, kq[3].w};
      #pragma unroll
      for (int j = 0; j < 8; ++j) {
        bh0[j] = (_Float16)f0[j];
        bh1[j] = (_Float16)f1[j];
      }
    }
    // prefetch next strip's k
    const int sn = s + 4;
    if (sn < 13) {
      const int trn = sn * 16 + r16;
      if (trn < TT) {
        kq[0] = *(const float4*)(kb + trn * DD + dof);
        kq[1] = *(const float4*)(kb + trn * DD + dof + 4);
        kq[2] = *(const float4*)(kb + trn * DD + 32 + dof);
        kq[3] = *(const float4*)(kb + trn * DD + 32 + dof + 4);
      } else {
        float4 z = {0.f, 0.f, 0.f, 0.f};
        kq[0] = z; kq[1] = z; kq[2] = z; kq[3] = z;
      }
    }

    f32x4 acc1[4];
    #pragma unroll
    for (int c1 = 0; c1 < 4; ++c1) acc1[c1] = (f32x4){0.f, 0.f, 0.f, 0.f};

    // m-loop over 32-row h-blocks; nothing register-resident indexed by m
    #pragma unroll 1
    for (int m = 0; m < 4; ++m) {
      const _Float16* rowE = &MhT[((2 * m) * 16 + r16) * MP];
      const _Float16* rowO = rowE + 16 * MP;
      // layer0 even c-block (rows 32m+4g4+r)
      f16x8 afE0 = *(const f16x8*)(rowE + dof);
      f16x8 afE1 = *(const f16x8*)(rowE + 32 + dof);
      f32x4 a0e = {0.f, 0.f, 0.f, 0.f};
      a0e = __builtin_amdgcn_mfma_f32_16x16x32_f16(afE0, bh0, a0e, 0, 0, 0);
      a0e = __builtin_amdgcn_mfma_f32_16x16x32_f16(afE1, bh1, a0e, 0, 0, 0);
      // layer0 odd c-block (rows 32m+16+4g4+r)
      f16x8 afO0 = *(const f16x8*)(rowO + dof);
      f16x8 afO1 = *(const f16x8*)(rowO + 32 + dof);
      f32x4 a0o = {0.f, 0.f, 0.f, 0.f};
      a0o = __builtin_amdgcn_mfma_f32_16x16x32_f16(afO0, bh0, a0o, 0, 0, 0);
      a0o = __builtin_amdgcn_mfma_f32_16x16x32_f16(afO1, bh1, a0o, 0, 0, 0);

      f32x4 cbe = *(const f32x4*)(&cbS[(2 * m) * 16 + 4 * g4]);
      f32x4 cbo = *(const f32x4*)(&cbS[(2 * m) * 16 + 16 + 4 * g4]);
      f16x8 hf;   // phi-layout: j<4 -> even block regs, j>=4 -> odd block regs
      #pragma unroll
      for (int r = 0; r < 4; ++r) {
        float he = a0e[r] + cbe[r];
        float ho = a0o[r] + cbo[r];
        hf[r]     = (_Float16)(he > 0.f ? he : 0.f);
        hf[4 + r] = (_Float16)(ho > 0.f ? ho : 0.f);
      }
      // layer1: A phi-permuted in LDS -> one b128 per (c1, m)
      #pragma unroll
      for (int c1 = 0; c1 < 4; ++c1) {
        f16x8 af1 = *(const f16x8*)(&W1p[(c1 * 16 + r16) * WP + m * 32 + dof]);
        acc1[c1] = __builtin_amdgcn_mfma_f32_16x16x32_f16(af1, hf, acc1[c1], 0, 0, 0);
      }
    }

    float p = 0.f;
    #pragma unroll
    for (int c1 = 0; c1 < 4; ++c1) {
      f32x4 b14 = *(const f32x4*)(&b1S[c1 * 16 + 4 * g4]);
      f32x4 wf4 = *(const f32x4*)(&WfS[c1 * 16 + 4 * g4]);
      #pragma unroll
      for (int r = 0; r < 4; ++r) {
        float h1 = acc1[c1][r] + b14[r];
        h1 = h1 > 0.f ? h1 : 0.f;
        p = fmaf(h1, wf4[r], p);
      }
    }

    p += __shfl_xor(p, 16, 64);
    p += __shfl_xor(p, 32, 64);
    p = (mm == 1) ? p : (mm == 0 ? -1e30f : -2e30f);
    if (g4 == 0) sP[t0 + r16] = p;
  }
  __syncthreads();

  // ---- pass 2: exact softmax over sP[0..207] ----
  float rcpS;
  {
    float val = (tid < 208) ? sP[tid] : -3e30f;
    float mx = val;
    #pragma unroll
    for (int off = 32; off >= 1; off >>= 1) mx = fmaxf(mx, __shfl_xor(mx, off, 64));
    if (lane == 0) red[wid] = mx;
    __syncthreads();
    float M = fmaxf(fmaxf(red[0], red[1]), fmaxf(red[2], red[3]));
    float e = (tid < 208) ? __expf(val - M) : 0.f;
    float se = e;
    #pragma unroll
    for (int off = 32; off >= 1; off >>= 1) se += __shfl_xor(se, off, 64);
    if (lane == 0) red[4 + wid] = se;
    __syncthreads();
    rcpS = 1.f / ((red[4] + red[5]) + (red[6] + red[7]));
    if (tid < 208) sP[tid] = e;
  }
  __syncthreads();

  // ---- pass 3: pooling, vectorized: lane = (tg = t mod 4, dq = d quarter) ----
  {
    const int tg = lane >> 4;       // 0..3 -> t offset within group of 4
    const int dq = lane & 15;       // 0..15 -> d quarter
    f32x4 o4 = {0.f, 0.f, 0.f, 0.f};
    const int tbase = wid * 52;
    #pragma unroll
    for (int i = 0; i < 13; ++i) {
      int t = tbase + i * 4 + tg;
      bool tv = t < TT;             // only wid==3, i==12 can exceed
      float w = tv ? sP[t] : 0.f;
      f32x4 v4 = tv ? *(const f32x4*)(vb + t * DD + dq * 4)
                    : (f32x4){0.f, 0.f, 0.f, 0.f};
      #pragma unroll
      for (int j = 0; j < 4; ++j) o4[j] = fmaf(w, v4[j], o4[j]);
    }
    #pragma unroll
    for (int j = 0; j < 4; ++j) {
      o4[j] += __shfl_xor(o4[j], 16, 64);
      o4[j] += __shfl_xor(o4[j], 32, 64);
    }
    if (tg == 0) *(f32x4*)(&pool[wid * 64 + dq * 4]) = o4;
  }
  __syncthreads();

  if (tid < DD)
    out[b * DD + tid] = ((pool[tid] + pool[64 + tid])
                       + (pool[128 + tid] + pool[192 + tid])) * rcpS;
}

extern "C" void kernel_launch(void* const* d_in, const int* in_sizes, int n_in,
                              void* d_out, int out_size, void* d_ws, size_t ws_size,
                              hipStream_t stream) {
  const float* q    = (const float*)d_in[0];
  const float* k    = (const float*)d_in[1];
  const float* v    = (const float*)d_in[2];
  const int*   mask = (const int*)d_in[3];
  const float* W0   = (const float*)d_in[4];
  const float* b0   = (const float*)d_in[5];
  const float* W1   = (const float*)d_in[6];
  const float* b1   = (const float*)d_in[7];
  const float* Wf   = (const float*)d_in[8];
  float* out = (float*)d_out;
  unsigned char* ws = (unsigned char*)d_ws;

  pre_fold<<<dim3(64), dim3(256), 0, stream>>>(W0, W1, ws);
  pre_cb<<<dim3(128), dim3(256), 0, stream>>>(q, W0, b0, ws);
  din_attn<<<dim3(NB), dim3(256), 0, stream>>>(q, k, v, mask, b1, Wf, ws, out);
}